// Round 1
// baseline (166.376 us; speedup 1.0000x reference)
//
#include <hip/hip_runtime.h>
#include <hip/hip_fp16.h>

using half8  = __attribute__((ext_vector_type(8))) _Float16;
using f32x4  = __attribute__((ext_vector_type(4))) float;
using uint4v = __attribute__((ext_vector_type(4))) unsigned int;

#define GROUPS      3333
#define BINNER_OUT  9999
#define BATCH       256
#define ROWS        512          // 2 spectra x 256
#define K1          9999
#define K1P         10016        // K1 padded to mult of 32
#define NP          1024         // hidden 1000 padded
#define NOP         512          // out 500 padded

// ---- h init: h32[r][k] = bg[k] -------------------------------------------
__global__ void init_h(const float* __restrict__ bg, float* __restrict__ h32) {
  int col = blockIdx.x * 256 + threadIdx.x;
  int row = blockIdx.y;
  if (col < BINNER_OUT) h32[(size_t)row * BINNER_OUT + col] = bg[col];
}

// ---- scatter peaks directly into grouped-linear output h ------------------
__global__ void scatter_peaks(const float* __restrict__ mz1, const float* __restrict__ it1,
                              const float* __restrict__ mz2, const float* __restrict__ it2,
                              const float* __restrict__ Wg, float* __restrict__ h32) {
  int t = blockIdx.x * 256 + threadIdx.x;   // 0 .. 262143
  int s = t >> 17;                          // spectrum 0/1
  int i = t & 131071;                       // flat [256*512] peak index
  float mz = s ? mz2[i] : mz1[i];
  float in = s ? it2[i] : it1[i];
  if (!(mz >= 0.0f && mz < 1000.0f)) return;
  int bin = (int)floorf(mz / 0.01f);        // IEEE div, matches jnp fp32
  bin = bin < 0 ? 0 : (bin > 99999 ? 99999 : bin);
  if (bin >= GROUPS * 30) return;           // bins 99990..99999 dropped
  int g = bin / 30;
  const float* w = Wg + (size_t)bin * 3;    // Wg[g][i][o] flat == Wg[bin*3+o]
  float* dst = h32 + (size_t)(s * BATCH + (i >> 9)) * BINNER_OUT + g * 3;
  atomicAdd(dst + 0, in * w[0]);
  atomicAdd(dst + 1, in * w[1]);
  atomicAdd(dst + 2, in * w[2]);
}

// ---- h32 -> fp16, zero-pad K to 10016 -------------------------------------
__global__ void cvt_h(const float* __restrict__ h32, _Float16* __restrict__ h16) {
  int col = blockIdx.x * 256 + threadIdx.x;
  int row = blockIdx.y;
  if (col < K1P)
    h16[(size_t)row * K1P + col] =
        (col < K1) ? (_Float16)h32[(size_t)row * K1 + col] : (_Float16)0.f;
}

// ---- weight transpose+convert: out[n*Kpad + k] = fp16(W[k*N + n]) ---------
__global__ void transp_cvt(const float* __restrict__ W, int K, int N, int Kpad,
                           _Float16* __restrict__ out) {
  __shared__ float tile[32][33];
  int k0 = blockIdx.x * 32, n0 = blockIdx.y * 32;
  int tx = threadIdx.x & 31, ty = threadIdx.x >> 5;   // ty 0..7
#pragma unroll
  for (int i = 0; i < 4; ++i) {
    int r = ty + i * 8;
    int k = k0 + r, n = n0 + tx;
    tile[r][tx] = (k < K && n < N) ? W[(size_t)k * N + n] : 0.f;
  }
  __syncthreads();
#pragma unroll
  for (int i = 0; i < 4; ++i) {
    int r = ty + i * 8;
    out[(size_t)(n0 + r) * Kpad + (k0 + tx)] = (_Float16)tile[tx][r];
  }
}

// ---- split-K fp16 MFMA GEMM: part[z] = A[M,K] * Bt[N,K]^T -----------------
// A row-major [M][lda], Bt k-major [Npad][ldb]. Tiles: 128x64, BK=32,
// 4 waves of 64x32. One 2-barrier phase per K-step (round-1 baseline).
template <int BM, int BN, int BK, int WM, int WN>
__global__ __launch_bounds__(256) void gemm_sk(
    const _Float16* __restrict__ A, int lda,
    const _Float16* __restrict__ Bt, int ldb,
    float* __restrict__ part, int M, int Npad, int ksteps_total, int kspc) {
  constexpr int WCOLS = BN / WN;
  constexpr int MI = WM / 16, NI = WN / 16;
  static_assert((BM / WM) * (BN / WN) * 64 == 256, "4 waves");
  static_assert(BM * BK == 256 * 16 && BN * BK == 256 * 8, "staging map");

  __shared__ __align__(16) _Float16 As[BM * BK];
  __shared__ __align__(16) _Float16 Bs[BN * BK];

  const int t  = threadIdx.x;
  const int m0 = blockIdx.y * BM;
  const int n0 = blockIdx.x * BN;
  const int z  = blockIdx.z;
  int s0 = z * kspc;
  int s1 = s0 + kspc; if (s1 > ksteps_total) s1 = ksteps_total;

  const int lane = t & 63, wid = t >> 6;
  const int wr = wid / WCOLS, wc = wid % WCOLS;
  const int r16 = lane & 15, kh = lane >> 4;

  // staging maps (256 threads): A tile BM x BK = 4096 fp16 -> 16/thread
  const int ra = t >> 1, sa = (t & 1) * 16;    // row, 16-elem segment
  const int nb = t >> 2, sb = (t & 3) * 8;     // B tile: 8/thread
  const _Float16* Ag = A  + (size_t)(m0 + ra) * lda + sa;
  const _Float16* Bg = Bt + (size_t)(n0 + nb) * ldb + sb;

  f32x4 acc[MI][NI] = {};

  for (int s = s0; s < s1; ++s) {
    const int k0 = s * BK;
    __syncthreads();
    *(uint4v*)&As[ra * BK + sa]     = *(const uint4v*)(Ag + k0);
    *(uint4v*)&As[ra * BK + sa + 8] = *(const uint4v*)(Ag + k0 + 8);
    *(uint4v*)&Bs[nb * BK + sb]     = *(const uint4v*)(Bg + k0);
    __syncthreads();

    half8 af[MI], bf[NI];
#pragma unroll
    for (int mi = 0; mi < MI; ++mi)
      af[mi] = *(const half8*)&As[(wr * WM + mi * 16 + r16) * BK + kh * 8];
#pragma unroll
    for (int ni = 0; ni < NI; ++ni)
      bf[ni] = *(const half8*)&Bs[(wc * WN + ni * 16 + r16) * BK + kh * 8];
#pragma unroll
    for (int mi = 0; mi < MI; ++mi)
#pragma unroll
      for (int ni = 0; ni < NI; ++ni)
        acc[mi][ni] = __builtin_amdgcn_mfma_f32_16x16x32_f16(
            af[mi], bf[ni], acc[mi][ni], 0, 0, 0);
  }

  float* P = part + (size_t)z * M * Npad;
#pragma unroll
  for (int mi = 0; mi < MI; ++mi)
#pragma unroll
    for (int ni = 0; ni < NI; ++ni) {
      int row = m0 + wr * WM + mi * 16 + kh * 4;       // C/D: row=(l>>4)*4+rr
      int col = n0 + wc * WN + ni * 16 + r16;          //      col=l&15
#pragma unroll
      for (int rr = 0; rr < 4; ++rr)
        P[(size_t)(row + rr) * Npad + col] = acc[mi][ni][rr];
    }
}

// ---- combine split-K partials + bias (+relu), emit fp16 or fp32 ----------
__global__ void combine_sk(const float* __restrict__ part, int SK, int M, int Npad,
                           const float* __restrict__ bias, int Nreal, int relu,
                           _Float16* __restrict__ o16, float* __restrict__ o32) {
  int idx = blockIdx.x * 256 + threadIdx.x;
  int total = M * Npad;
  if (idx >= total) return;
  int n = idx & (Npad - 1);  // Npad is a power of two
  float s = 0.f;
  for (int zz = 0; zz < SK; ++zz) s += part[(size_t)zz * total + idx];
  s += (n < Nreal) ? bias[n] : 0.f;
  if (relu) s = fmaxf(s, 0.f);
  if (o16) o16[idx] = (_Float16)s;
  else     o32[idx] = s;
}

// ---- cosine similarity out[b] = e1.e2 / (max(|e1|,eps)*max(|e2|,eps)) -----
__global__ void cosine_kernel(const float* __restrict__ E, float* __restrict__ out) {
  int b = blockIdx.x;
  const float* e1 = E + (size_t)b * NOP;
  const float* e2 = E + (size_t)(b + BATCH) * NOP;
  int t = threadIdx.x;
  float d = 0.f, s1 = 0.f, s2 = 0.f;
  for (int c = t; c < NOP; c += 256) {
    float a = e1[c], bb = e2[c];
    d += a * bb; s1 += a * a; s2 += bb * bb;
  }
  for (int off = 32; off > 0; off >>= 1) {
    d  += __shfl_down(d, off, 64);
    s1 += __shfl_down(s1, off, 64);
    s2 += __shfl_down(s2, off, 64);
  }
  __shared__ float rd[4], r1[4], r2[4];
  int wid = t >> 6, lane = t & 63;
  if (lane == 0) { rd[wid] = d; r1[wid] = s1; r2[wid] = s2; }
  __syncthreads();
  if (t == 0) {
    float D  = rd[0] + rd[1] + rd[2] + rd[3];
    float S1 = r1[0] + r1[1] + r1[2] + r1[3];
    float S2 = r2[0] + r2[1] + r2[2] + r2[3];
    float n1 = fmaxf(sqrtf(S1), 1e-6f);
    float n2 = fmaxf(sqrtf(S2), 1e-6f);
    out[b] = D / (n1 * n2);
  }
}

extern "C" void kernel_launch(void* const* d_in, const int* in_sizes, int n_in,
                              void* d_out, int out_size, void* d_ws, size_t ws_size,
                              hipStream_t stream) {
  const float* mz1 = (const float*)d_in[0];
  const float* it1 = (const float*)d_in[1];
  const float* mz2 = (const float*)d_in[2];
  const float* it2 = (const float*)d_in[3];
  const float* Wg  = (const float*)d_in[4];
  const float* bg  = (const float*)d_in[5];
  const float* W1  = (const float*)d_in[6];
  const float* b1  = (const float*)d_in[7];
  const float* W2  = (const float*)d_in[8];
  const float* b2  = (const float*)d_in[9];
  const float* W3  = (const float*)d_in[10];
  const float* b3  = (const float*)d_in[11];
  const float* Wo  = (const float*)d_in[12];
  const float* bo  = (const float*)d_in[13];
  float* out = (float*)d_out;

  char* ws = (char*)d_ws;
  size_t off = 0;
  auto take = [&](size_t bytes) {
    size_t o = off; off += (bytes + 255) & ~(size_t)255; return o;
  };
  float*    h32  = (float*)   (ws + take((size_t)ROWS * K1 * 4));   // 20.5MB
  float*    part = h32;  // reuse: split-K partials (max 16MB) after cvt_h
  _Float16* h16  = (_Float16*)(ws + take((size_t)ROWS * K1P * 2));
  _Float16* W1t  = (_Float16*)(ws + take((size_t)NP * K1P * 2));
  _Float16* W2t  = (_Float16*)(ws + take((size_t)NP * NP * 2));
  _Float16* W3t  = (_Float16*)(ws + take((size_t)NP * NP * 2));
  _Float16* Wot  = (_Float16*)(ws + take((size_t)NOP * NP * 2));
  _Float16* y1   = (_Float16*)(ws + take((size_t)ROWS * NP * 2));
  _Float16* y2   = (_Float16*)(ws + take((size_t)ROWS * NP * 2));
  _Float16* y3   = (_Float16*)(ws + take((size_t)ROWS * NP * 2));
  float*    E    = (float*)   (ws + take((size_t)ROWS * NOP * 4));

  // 1) grouped-linear output h, built sparsely from peaks
  init_h<<<dim3(40, ROWS), 256, 0, stream>>>(bg, h32);
  scatter_peaks<<<1024, 256, 0, stream>>>(mz1, it1, mz2, it2, Wg, h32);
  cvt_h<<<dim3((K1P + 255) / 256, ROWS), 256, 0, stream>>>(h32, h16);

  // 2) weights -> fp16, transposed to [N][Kpad], zero-padded
  transp_cvt<<<dim3(K1P / 32, NP / 32),  256, 0, stream>>>(W1, K1,   1000, K1P, W1t);
  transp_cvt<<<dim3(NP / 32,  NP / 32),  256, 0, stream>>>(W2, 1000, 1000, NP,  W2t);
  transp_cvt<<<dim3(NP / 32,  NP / 32),  256, 0, stream>>>(W3, 1000, 1000, NP,  W3t);
  transp_cvt<<<dim3(NP / 32,  NOP / 32), 256, 0, stream>>>(Wo, 1000, 500,  NP,  Wot);

  // 3) MLP: L1 (K=10016, SK=8), L2/L3 (K=1024, SK=4), Lo (N=512, SK=8)
  gemm_sk<128, 64, 32, 64, 32><<<dim3(NP / 64, ROWS / 128, 8), 256, 0, stream>>>(
      h16, K1P, W1t, K1P, part, ROWS, NP, K1P / 32, 40);
  combine_sk<<<(ROWS * NP) / 256, 256, 0, stream>>>(part, 8, ROWS, NP, b1, 1000, 1, y1, nullptr);

  gemm_sk<128, 64, 32, 64, 32><<<dim3(NP / 64, ROWS / 128, 4), 256, 0, stream>>>(
      y1, NP, W2t, NP, part, ROWS, NP, NP / 32, 8);
  combine_sk<<<(ROWS * NP) / 256, 256, 0, stream>>>(part, 4, ROWS, NP, b2, 1000, 1, y2, nullptr);

  gemm_sk<128, 64, 32, 64, 32><<<dim3(NP / 64, ROWS / 128, 4), 256, 0, stream>>>(
      y2, NP, W3t, NP, part, ROWS, NP, NP / 32, 8);
  combine_sk<<<(ROWS * NP) / 256, 256, 0, stream>>>(part, 4, ROWS, NP, b3, 1000, 1, y3, nullptr);

  gemm_sk<128, 64, 32, 64, 32><<<dim3(NOP / 64, ROWS / 128, 8), 256, 0, stream>>>(
      y3, NP, Wot, NP, part, ROWS, NOP, NP / 32, 4);
  combine_sk<<<(ROWS * NOP) / 256, 256, 0, stream>>>(part, 8, ROWS, NOP, bo, 500, 0, nullptr, E);

  // 4) cosine similarity
  cosine_kernel<<<BATCH, 256, 0, stream>>>(E, out);
}

// Round 2
// 124.228 us; speedup vs baseline: 1.3393x; 1.3393x over previous
//
#include <hip/hip_runtime.h>
#include <hip/hip_fp16.h>

using half8  = __attribute__((ext_vector_type(8))) _Float16;
using f32x4  = __attribute__((ext_vector_type(4))) float;
using uint4v = __attribute__((ext_vector_type(4))) unsigned int;

#define GROUPS      3333
#define BINNER_OUT  9999
#define BATCH       256
#define ROWS        512          // 2 spectra x 256
#define PEAKS       512
#define K1          9999
#define K1P         10016        // K1 padded to mult of 32
#define NP          1024         // hidden 1000 padded
#define NOP         512          // out 500 padded

// ---- fused binning: per-row LDS accumulator -------------------------------
// One block per output row. Zero 9999-float LDS hist of grouped-linear
// outputs, scatter 512 peaks via LDS atomics, then emit fp16 h row
// (+bias, zero-padded to K1P) with 16B stores.
__global__ __launch_bounds__(256) void fused_bin(
    const float* __restrict__ mz1, const float* __restrict__ it1,
    const float* __restrict__ mz2, const float* __restrict__ it2,
    const float* __restrict__ Wg,  const float* __restrict__ bg,
    _Float16* __restrict__ h16) {
  __shared__ float hs[K1P];                 // 40064 B
  const int t = threadIdx.x;
  const int row = blockIdx.x;               // 0..511
  const int s = row >> 8, b = row & 255;

  // zero LDS (vectorized)
#pragma unroll
  for (int k = t * 4; k < K1P; k += 1024)
    *(f32x4*)&hs[k] = (f32x4){0.f, 0.f, 0.f, 0.f};
  __syncthreads();

  const float* mz = (s ? mz2 : mz1) + (size_t)b * PEAKS;
  const float* it = (s ? it2 : it1) + (size_t)b * PEAKS;
#pragma unroll
  for (int p = t; p < PEAKS; p += 256) {
    float m = mz[p], in = it[p];
    if (m >= 0.0f && m < 1000.0f) {
      int bin = (int)floorf(m / 0.01f);     // IEEE fp32 div+floor, matches jnp
      bin = bin < 0 ? 0 : (bin > 99999 ? 99999 : bin);
      if (bin < GROUPS * 30) {              // bins 99990..99999 dropped by ref
        int g = bin / 30;
        const float* w = Wg + (size_t)bin * 3;   // Wg[g][i][o] flat
        atomicAdd(&hs[g * 3 + 0], in * w[0]);
        atomicAdd(&hs[g * 3 + 1], in * w[1]);
        atomicAdd(&hs[g * 3 + 2], in * w[2]);
      }
    }
  }
  __syncthreads();

  // emit h16[row][0..K1P) = fp16(hs + bg), padding exact zero
  _Float16* dst = h16 + (size_t)row * K1P;
  for (int k0 = t * 8; k0 < K1P; k0 += 2048) {
    half8 v;
#pragma unroll
    for (int j = 0; j < 8; ++j) {
      int k = k0 + j;
      float x = hs[k] + (k < BINNER_OUT ? bg[k] : 0.f);
      v[j] = (_Float16)x;
    }
    *(half8*)(dst + k0) = v;
  }
}

// ---- weight transpose+convert: out[n*Kpad + k] = fp16(W[k*N + n]) ---------
__global__ void transp_cvt(const float* __restrict__ W, int K, int N, int Kpad,
                           _Float16* __restrict__ out) {
  __shared__ float tile[32][33];
  int k0 = blockIdx.x * 32, n0 = blockIdx.y * 32;
  int tx = threadIdx.x & 31, ty = threadIdx.x >> 5;   // ty 0..7
#pragma unroll
  for (int i = 0; i < 4; ++i) {
    int r = ty + i * 8;
    int k = k0 + r, n = n0 + tx;
    tile[r][tx] = (k < K && n < N) ? W[(size_t)k * N + n] : 0.f;
  }
  __syncthreads();
#pragma unroll
  for (int i = 0; i < 4; ++i) {
    int r = ty + i * 8;
    out[(size_t)(n0 + r) * Kpad + (k0 + tx)] = (_Float16)tile[tx][r];
  }
}

// ---- split-K fp16 MFMA GEMM: part[z] = A[M,K] * Bt[N,K]^T -----------------
// A row-major [M][lda], Bt k-major [Npad][ldb]. Tiles: 128x64, BK=32,
// 4 waves of 64x32. One 2-barrier phase per K-step.
template <int BM, int BN, int BK, int WM, int WN>
__global__ __launch_bounds__(256) void gemm_sk(
    const _Float16* __restrict__ A, int lda,
    const _Float16* __restrict__ Bt, int ldb,
    float* __restrict__ part, int M, int Npad, int ksteps_total, int kspc) {
  constexpr int WCOLS = BN / WN;
  constexpr int MI = WM / 16, NI = WN / 16;
  static_assert((BM / WM) * (BN / WN) * 64 == 256, "4 waves");
  static_assert(BM * BK == 256 * 16 && BN * BK == 256 * 8, "staging map");

  __shared__ __align__(16) _Float16 As[BM * BK];
  __shared__ __align__(16) _Float16 Bs[BN * BK];

  const int t  = threadIdx.x;
  const int m0 = blockIdx.y * BM;
  const int n0 = blockIdx.x * BN;
  const int z  = blockIdx.z;
  int s0 = z * kspc;
  int s1 = s0 + kspc; if (s1 > ksteps_total) s1 = ksteps_total;

  const int lane = t & 63, wid = t >> 6;
  const int wr = wid / WCOLS, wc = wid % WCOLS;
  const int r16 = lane & 15, kh = lane >> 4;

  // staging maps (256 threads): A tile BM x BK = 4096 fp16 -> 16/thread
  const int ra = t >> 1, sa = (t & 1) * 16;    // row, 16-elem segment
  const int nb = t >> 2, sb = (t & 3) * 8;     // B tile: 8/thread
  const _Float16* Ag = A  + (size_t)(m0 + ra) * lda + sa;
  const _Float16* Bg = Bt + (size_t)(n0 + nb) * ldb + sb;

  f32x4 acc[MI][NI] = {};

  for (int s = s0; s < s1; ++s) {
    const int k0 = s * BK;
    __syncthreads();
    *(uint4v*)&As[ra * BK + sa]     = *(const uint4v*)(Ag + k0);
    *(uint4v*)&As[ra * BK + sa + 8] = *(const uint4v*)(Ag + k0 + 8);
    *(uint4v*)&Bs[nb * BK + sb]     = *(const uint4v*)(Bg + k0);
    __syncthreads();

    half8 af[MI], bf[NI];
#pragma unroll
    for (int mi = 0; mi < MI; ++mi)
      af[mi] = *(const half8*)&As[(wr * WM + mi * 16 + r16) * BK + kh * 8];
#pragma unroll
    for (int ni = 0; ni < NI; ++ni)
      bf[ni] = *(const half8*)&Bs[(wc * WN + ni * 16 + r16) * BK + kh * 8];
#pragma unroll
    for (int mi = 0; mi < MI; ++mi)
#pragma unroll
      for (int ni = 0; ni < NI; ++ni)
        acc[mi][ni] = __builtin_amdgcn_mfma_f32_16x16x32_f16(
            af[mi], bf[ni], acc[mi][ni], 0, 0, 0);
  }

  float* P = part + (size_t)z * M * Npad;
#pragma unroll
  for (int mi = 0; mi < MI; ++mi)
#pragma unroll
    for (int ni = 0; ni < NI; ++ni) {
      int row = m0 + wr * WM + mi * 16 + kh * 4;       // C/D: row=(l>>4)*4+rr
      int col = n0 + wc * WN + ni * 16 + r16;          //      col=l&15
#pragma unroll
      for (int rr = 0; rr < 4; ++rr)
        P[(size_t)(row + rr) * Npad + col] = acc[mi][ni][rr];
    }
}

// ---- combine split-K partials + bias (+relu), emit fp16 or fp32 ----------
__global__ void combine_sk(const float* __restrict__ part, int SK, int M, int Npad,
                           const float* __restrict__ bias, int Nreal, int relu,
                           _Float16* __restrict__ o16, float* __restrict__ o32) {
  int idx = blockIdx.x * 256 + threadIdx.x;
  int total = M * Npad;
  if (idx >= total) return;
  int n = idx & (Npad - 1);  // Npad is a power of two
  float s = 0.f;
  for (int zz = 0; zz < SK; ++zz) s += part[(size_t)zz * total + idx];
  s += (n < Nreal) ? bias[n] : 0.f;
  if (relu) s = fmaxf(s, 0.f);
  if (o16) o16[idx] = (_Float16)s;
  else     o32[idx] = s;
}

// ---- cosine similarity out[b] = e1.e2 / (max(|e1|,eps)*max(|e2|,eps)) -----
__global__ void cosine_kernel(const float* __restrict__ E, float* __restrict__ out) {
  int b = blockIdx.x;
  const float* e1 = E + (size_t)b * NOP;
  const float* e2 = E + (size_t)(b + BATCH) * NOP;
  int t = threadIdx.x;
  float d = 0.f, s1 = 0.f, s2 = 0.f;
  for (int c = t; c < NOP; c += 256) {
    float a = e1[c], bb = e2[c];
    d += a * bb; s1 += a * a; s2 += bb * bb;
  }
  for (int off = 32; off > 0; off >>= 1) {
    d  += __shfl_down(d, off, 64);
    s1 += __shfl_down(s1, off, 64);
    s2 += __shfl_down(s2, off, 64);
  }
  __shared__ float rd[4], r1[4], r2[4];
  int wid = t >> 6, lane = t & 63;
  if (lane == 0) { rd[wid] = d; r1[wid] = s1; r2[wid] = s2; }
  __syncthreads();
  if (t == 0) {
    float D  = rd[0] + rd[1] + rd[2] + rd[3];
    float S1 = r1[0] + r1[1] + r1[2] + r1[3];
    float S2 = r2[0] + r2[1] + r2[2] + r2[3];
    float n1 = fmaxf(sqrtf(S1), 1e-6f);
    float n2 = fmaxf(sqrtf(S2), 1e-6f);
    out[b] = D / (n1 * n2);
  }
}

extern "C" void kernel_launch(void* const* d_in, const int* in_sizes, int n_in,
                              void* d_out, int out_size, void* d_ws, size_t ws_size,
                              hipStream_t stream) {
  const float* mz1 = (const float*)d_in[0];
  const float* it1 = (const float*)d_in[1];
  const float* mz2 = (const float*)d_in[2];
  const float* it2 = (const float*)d_in[3];
  const float* Wg  = (const float*)d_in[4];
  const float* bg  = (const float*)d_in[5];
  const float* W1  = (const float*)d_in[6];
  const float* b1  = (const float*)d_in[7];
  const float* W2  = (const float*)d_in[8];
  const float* b2  = (const float*)d_in[9];
  const float* W3  = (const float*)d_in[10];
  const float* b3  = (const float*)d_in[11];
  const float* Wo  = (const float*)d_in[12];
  const float* bo  = (const float*)d_in[13];
  float* out = (float*)d_out;

  char* ws = (char*)d_ws;
  size_t off = 0;
  auto take = [&](size_t bytes) {
    size_t o = off; off += (bytes + 255) & ~(size_t)255; return o;
  };
  float*    part = (float*)   (ws + take((size_t)8 * ROWS * NP * 4));  // 16MB
  _Float16* h16  = (_Float16*)(ws + take((size_t)ROWS * K1P * 2));
  _Float16* W1t  = (_Float16*)(ws + take((size_t)NP * K1P * 2));
  _Float16* W2t  = (_Float16*)(ws + take((size_t)NP * NP * 2));
  _Float16* W3t  = (_Float16*)(ws + take((size_t)NP * NP * 2));
  _Float16* Wot  = (_Float16*)(ws + take((size_t)NOP * NP * 2));
  _Float16* y1   = (_Float16*)(ws + take((size_t)ROWS * NP * 2));
  _Float16* y2   = (_Float16*)(ws + take((size_t)ROWS * NP * 2));
  _Float16* y3   = (_Float16*)(ws + take((size_t)ROWS * NP * 2));
  float*    E    = (float*)   (ws + take((size_t)ROWS * NOP * 4));

  // 1) binning + grouped linear + bias + fp16 conversion, fused per row
  fused_bin<<<ROWS, 256, 0, stream>>>(mz1, it1, mz2, it2, Wg, bg, h16);

  // 2) weights -> fp16, transposed to [N][Kpad], zero-padded
  transp_cvt<<<dim3(K1P / 32, NP / 32),  256, 0, stream>>>(W1, K1,   1000, K1P, W1t);
  transp_cvt<<<dim3(NP / 32,  NP / 32),  256, 0, stream>>>(W2, 1000, 1000, NP,  W2t);
  transp_cvt<<<dim3(NP / 32,  NP / 32),  256, 0, stream>>>(W3, 1000, 1000, NP,  W3t);
  transp_cvt<<<dim3(NP / 32,  NOP / 32), 256, 0, stream>>>(Wo, 1000, 500,  NP,  Wot);

  // 3) MLP: L1 (K=10016, SK=8), L2/L3 (K=1024, SK=4), Lo (N=512, SK=8)
  gemm_sk<128, 64, 32, 64, 32><<<dim3(NP / 64, ROWS / 128, 8), 256, 0, stream>>>(
      h16, K1P, W1t, K1P, part, ROWS, NP, K1P / 32, 40);
  combine_sk<<<(ROWS * NP) / 256, 256, 0, stream>>>(part, 8, ROWS, NP, b1, 1000, 1, y1, nullptr);

  gemm_sk<128, 64, 32, 64, 32><<<dim3(NP / 64, ROWS / 128, 4), 256, 0, stream>>>(
      y1, NP, W2t, NP, part, ROWS, NP, NP / 32, 8);
  combine_sk<<<(ROWS * NP) / 256, 256, 0, stream>>>(part, 4, ROWS, NP, b2, 1000, 1, y2, nullptr);

  gemm_sk<128, 64, 32, 64, 32><<<dim3(NP / 64, ROWS / 128, 4), 256, 0, stream>>>(
      y2, NP, W3t, NP, part, ROWS, NP, NP / 32, 8);
  combine_sk<<<(ROWS * NP) / 256, 256, 0, stream>>>(part, 4, ROWS, NP, b3, 1000, 1, y3, nullptr);

  gemm_sk<128, 64, 32, 64, 32><<<dim3(NOP / 64, ROWS / 128, 8), 256, 0, stream>>>(
      y3, NP, Wot, NP, part, ROWS, NOP, NP / 32, 4);
  combine_sk<<<(ROWS * NOP) / 256, 256, 0, stream>>>(part, 8, ROWS, NOP, bo, 500, 0, nullptr, E);

  // 4) cosine similarity
  cosine_kernel<<<BATCH, 256, 0, stream>>>(E, out);
}